// Round 1
// baseline (601.561 us; speedup 1.0000x reference)
//
#include <hip/hip_runtime.h>

// Problem: segment-mean of x[:,0] over sorted `batch` -> out[4096]
//   x:          (1e6, 128) f32   (d_in[0])  -- only column 0 used
//   edge_index: (2, 1e6)   int   (d_in[1])  -- UNUSED by reference
//   edge_attr:  (1e6, 16)  f32   (d_in[2])  -- UNUSED by reference
//   batch:      (1e6,)     int   (d_in[3])  -- sorted, values in [0, 4096)
// out[g] = sum(x[i,0] for batch[i]==g) / count(batch[i]==g)

#define N_GRAPHS 4096
#define D_FEAT   128

__global__ void zero_ws_kernel(float* ws, int n) {
    int i = blockIdx.x * blockDim.x + threadIdx.x;
    if (i < n) ws[i] = 0.0f;
}

// Wave-level segmented reduction over sorted batch ids.
// Because batch is sorted, runs are contiguous: seg[lane-off]==seg[lane]
// implies every lane in between shares the segment, so a plain shfl-up
// segmented inclusive scan is correct.
__global__ __launch_bounds__(256) void accum_kernel(
        const float* __restrict__ x,
        const int*   __restrict__ batch,
        float* __restrict__ sums,
        float* __restrict__ counts,
        int n) {
    int i    = blockIdx.x * blockDim.x + threadIdx.x;
    int lane = threadIdx.x & 63;

    bool  valid = (i < n);
    int   seg   = valid ? batch[i] : -1;          // -1 never matches a real seg
    float sum   = valid ? x[(size_t)i * D_FEAT] : 0.0f;
    float cnt   = valid ? 1.0f : 0.0f;

    // Segmented inclusive scan across the 64-lane wave (all lanes active).
    #pragma unroll
    for (int off = 1; off < 64; off <<= 1) {
        float s2 = __shfl_up(sum, off);
        float c2 = __shfl_up(cnt, off);
        int   g2 = __shfl_up(seg, off);
        if (lane >= off && g2 == seg) { sum += s2; cnt += c2; }
    }

    // Tail of a run (last lane of wave, or next lane starts a new segment)
    // holds the full run total -> one atomic pair per run (~1-2 per wave).
    int  seg_next = __shfl_down(seg, 1);
    bool tail     = (lane == 63) || (seg_next != seg);
    if (valid && tail) {
        atomicAdd(sums + seg, sum);
        atomicAdd(counts + seg, cnt);
    }
}

__global__ void finalize_kernel(const float* __restrict__ sums,
                                const float* __restrict__ counts,
                                float* __restrict__ out, int n) {
    int g = blockIdx.x * blockDim.x + threadIdx.x;
    if (g < n) out[g] = sums[g] / counts[g];
}

extern "C" void kernel_launch(void* const* d_in, const int* in_sizes, int n_in,
                              void* d_out, int out_size, void* d_ws, size_t ws_size,
                              hipStream_t stream) {
    const float* x     = (const float*)d_in[0];
    const int*   batch = (const int*)  d_in[3];
    int n_nodes = in_sizes[3];            // 1,000,000

    float* sums   = (float*)d_ws;         // [N_GRAPHS]
    float* counts = sums + N_GRAPHS;      // [N_GRAPHS]

    // 1) zero the accumulators (d_ws is poisoned 0xAA before every launch)
    {
        int n = 2 * N_GRAPHS;
        zero_ws_kernel<<<(n + 255) / 256, 256, 0, stream>>>((float*)d_ws, n);
    }

    // 2) accumulate per-segment sums and counts
    accum_kernel<<<(n_nodes + 255) / 256, 256, 0, stream>>>(
        x, batch, sums, counts, n_nodes);

    // 3) divide
    finalize_kernel<<<(out_size + 255) / 256, 256, 0, stream>>>(
        sums, counts, (float*)d_out, out_size);
}

// Round 2
// 590.707 us; speedup vs baseline: 1.0184x; 1.0184x over previous
//
#include <hip/hip_runtime.h>

// Problem: segment-mean of x[:,0] over sorted `batch` -> out[4096]
//   x:          (1e6, 128) f32   (d_in[0])  -- only column 0 used (stride-512B gather)
//   edge_index: (2, 1e6)   int   (d_in[1])  -- UNUSED
//   edge_attr:  (1e6, 16)  f32   (d_in[2])  -- UNUSED
//   batch:      (1e6,)     int   (d_in[3])  -- SORTED, values in [0, 4096)
//
// Design: 4 nodes/thread (int4 batch load = coalesced 16B/lane; 4 outstanding
// x-gathers/lane). Uniform chunks (b.x==b.w, ~98.8%) enter a 64-lane
// segmented shfl-up scan (valid because batch is sorted: equal segs at
// distance `off` implies the whole span is equal; a boundary-chunk sentinel
// lane can never separate two same-seg lanes, by sortedness). Boundary
// chunks flush their runs via direct atomics (~3k threads). One atomic pair
// per cross-thread run tail => ~65k atomics total over 4096 addresses.

#define N_GRAPHS 4096
#define D_FEAT   128

__global__ __launch_bounds__(256) void zero_ws_kernel(float* ws, int n) {
    int i = blockIdx.x * blockDim.x + threadIdx.x;
    if (i < n) ws[i] = 0.0f;
}

__global__ __launch_bounds__(256) void accum_kernel(
        const float* __restrict__ x,
        const int*   __restrict__ batch,
        float* __restrict__ sums,
        float* __restrict__ counts,
        int n_chunks, int n) {
    int t    = blockIdx.x * blockDim.x + threadIdx.x;
    int lane = threadIdx.x & 63;

    int   seg = -1;
    float sum = 0.0f, cnt = 0.0f;

    if (t < n_chunks) {
        size_t base = (size_t)t * 4;
        if (base + 3 < (size_t)n) {
            int4 b = ((const int4*)batch)[t];
            float v0 = __builtin_nontemporal_load(&x[(base + 0) * D_FEAT]);
            float v1 = __builtin_nontemporal_load(&x[(base + 1) * D_FEAT]);
            float v2 = __builtin_nontemporal_load(&x[(base + 2) * D_FEAT]);
            float v3 = __builtin_nontemporal_load(&x[(base + 3) * D_FEAT]);
            if (b.x == b.w) {
                // uniform chunk (common): one piece for the wave scan
                seg = b.x; sum = v0 + v1 + v2 + v3; cnt = 4.0f;
            } else {
                // boundary chunk (rare): flush runs directly, stay sentinel
                int   bs[4] = {b.x, b.y, b.z, b.w};
                float vs[4] = {v0, v1, v2, v3};
                int cs = bs[0]; float s = vs[0], c = 1.0f;
                #pragma unroll
                for (int j = 1; j < 4; ++j) {
                    if (bs[j] == cs) { s += vs[j]; c += 1.0f; }
                    else {
                        atomicAdd(sums + cs, s); atomicAdd(counts + cs, c);
                        cs = bs[j]; s = vs[j]; c = 1.0f;
                    }
                }
                atomicAdd(sums + cs, s); atomicAdd(counts + cs, c);
            }
        } else {
            // partial tail chunk (n % 4 != 0): scalar, direct atomics
            for (size_t j = base; j < (size_t)n; ++j) {
                int g = batch[j];
                atomicAdd(sums + g, x[j * D_FEAT]);
                atomicAdd(counts + g, 1.0f);
            }
        }
    }

    // Segmented inclusive scan across the 64-lane wave.
    #pragma unroll
    for (int off = 1; off < 64; off <<= 1) {
        float s2 = __shfl_up(sum, off);
        float c2 = __shfl_up(cnt, off);
        int   g2 = __shfl_up(seg, off);
        if (lane >= off && g2 == seg) { sum += s2; cnt += c2; }
    }

    // Run tails flush once per cross-thread run.
    int  seg_next = __shfl_down(seg, 1);
    bool tail     = (lane == 63) || (seg_next != seg);
    if (seg >= 0 && tail) {
        atomicAdd(sums + seg, sum);
        atomicAdd(counts + seg, cnt);
    }
}

__global__ __launch_bounds__(256) void finalize_kernel(
        const float* __restrict__ sums,
        const float* __restrict__ counts,
        float* __restrict__ out, int n) {
    int g = blockIdx.x * blockDim.x + threadIdx.x;
    if (g < n) out[g] = sums[g] / counts[g];
}

extern "C" void kernel_launch(void* const* d_in, const int* in_sizes, int n_in,
                              void* d_out, int out_size, void* d_ws, size_t ws_size,
                              hipStream_t stream) {
    const float* x     = (const float*)d_in[0];
    const int*   batch = (const int*)  d_in[3];
    int n_nodes = in_sizes[3];                 // 1,000,000

    float* sums   = (float*)d_ws;              // [N_GRAPHS]
    float* counts = sums + N_GRAPHS;           // [N_GRAPHS]

    // 1) zero accumulators (ws is poisoned 0xAA before every timed launch)
    {
        int n = 2 * N_GRAPHS;
        zero_ws_kernel<<<(n + 255) / 256, 256, 0, stream>>>((float*)d_ws, n);
    }

    // 2) accumulate per-segment (sum, count), 4 nodes per thread
    int n_chunks = (n_nodes + 3) / 4;          // 250,000
    accum_kernel<<<(n_chunks + 255) / 256, 256, 0, stream>>>(
        x, batch, sums, counts, n_chunks, n_nodes);

    // 3) divide
    finalize_kernel<<<(out_size + 255) / 256, 256, 0, stream>>>(
        sums, counts, (float*)d_out, out_size);
}